// Round 3
// baseline (1005.010 us; speedup 1.0000x reference)
//
#include <hip/hip_runtime.h>
#include <stdint.h>

// HybridCodebook forward, MFMA edition, R3.
//   xn = normalize(x); cb = [normalize(sem); normalize(learn)]
//   logits = xn @ cb^T ; indices = argmax ; z_q = cb[indices]; losses.
// Outputs (f32, flat): logits [8192*8320], indices [8192], z_q [8192*1024],
//   z_q_st [8192*1024], vq_loss, commitment_loss, quant_loss.
//
// R3 changes vs R2 (884 us: GEMM 549 + ~335 non-GEMM):
//  (a) GEMM was stall-bound: cycle budget per CU-K-step = 1860 MFMA / 1540 LDS
//      vs ~4900 measured -> 63% stall at the stage->vmcnt(0)->barrier drain
//      with only 2 blocks/CU. Fixes:
//        - LO operands no longer staged in LDS: aL/bL fragments loaded per-lane
//          directly from global (L2-hot; 2x redundancy within block). LDS
//          arrays 4 -> 2 (hi only, dbuf) = 32 KB -> 3 blocks/CU; LDS-read
//          traffic halved; gload_lds per K-step 8 -> 4.
//        - 2-phase prefetch (T3-minimum): STAGE(next) issued BEFORE compute of
//          current tile; one raw s_barrier + vmcnt(0) per K-step (loads drain
//          after ~1800cy of compute, not immediately).
//  (b) k_init + 3x k_norm_split merged into one k_prep launch.
//
// fp16 2-split numerics (hi+lo, drop lo*lo): absmax 4.88e-4 passing since R1.
// Split staging aliases output buffer: x hi/lo fills o_zq exactly, sem hi/lo
// fills o_zst exactly; both overwritten only by k_epilogue AFTER the GEMM.

#define N_TOK   8192
#define DIM     1024
#define N_SEM   8192
#define N_LEARN 128
#define N_CODE  (N_SEM + N_LEARN)   // 8320

typedef _Float16 f16;
typedef _Float16 f16x4 __attribute__((ext_vector_type(4)));
typedef _Float16 f16x8 __attribute__((ext_vector_type(8)));
typedef float    f32x4 __attribute__((ext_vector_type(4)));

// ---- K1: per-row inverse L2 norm + fp16 hi/lo split write (x|sem|lrn fused),
//          plus keys zeroing (ws is poisoned 0xAA) ----
__global__ __launch_bounds__(256) void k_prep(
    const float* __restrict__ x,   float* __restrict__ invnx,
    f16* __restrict__ xHi,  f16* __restrict__ xLo,
    const float* __restrict__ sem, float* __restrict__ invnb,
    f16* __restrict__ semHi, f16* __restrict__ semLo,
    const float* __restrict__ lrn,
    f16* __restrict__ lrnHi, f16* __restrict__ lrnLo,
    unsigned long long* __restrict__ keys)
{
    const int b = blockIdx.x;
    const int t = threadIdx.x;
    const float* in; float* invn; f16* hi; f16* lo; int row;
    if (b < N_TOK) {
        row = b; in = x; invn = invnx; hi = xHi; lo = xLo;
        if (t == 0) keys[row] = 0ULL;
    } else if (b < N_TOK + N_SEM) {
        row = b - N_TOK; in = sem; invn = invnb; hi = semHi; lo = semLo;
    } else {
        row = b - N_TOK - N_SEM; in = lrn; invn = invnb + N_SEM;
        hi = lrnHi; lo = lrnLo;
    }

    float4 v = ((const float4*)(in + (size_t)row * DIM))[t];
    float ss = v.x*v.x + v.y*v.y + v.z*v.z + v.w*v.w;
    #pragma unroll
    for (int off = 32; off > 0; off >>= 1) ss += __shfl_xor(ss, off);
    __shared__ float red[4];
    if ((t & 63) == 0) red[t >> 6] = ss;

    f16 h0 = (f16)v.x, h1 = (f16)v.y, h2 = (f16)v.z, h3 = (f16)v.w;
    f16x4 hv = {h0, h1, h2, h3};
    f16x4 lv = {(f16)(v.x - (float)h0), (f16)(v.y - (float)h1),
                (f16)(v.z - (float)h2), (f16)(v.w - (float)h3)};
    ((f16x4*)(hi + (size_t)row * DIM))[t] = hv;
    ((f16x4*)(lo + (size_t)row * DIM))[t] = lv;

    __syncthreads();
    if (t == 0) {
        float tot = red[0] + red[1] + red[2] + red[3];
        invn[row] = 1.f / fmaxf(sqrtf(tot), 1e-8f);
    }
}

// ---- K2: fp16-split MFMA GEMM + scaled f32 logits store + packed argmax ----
#define BM 128
#define BN 128
#define BK 32

__device__ __forceinline__ void gload16(const void* g, void* l) {
    __builtin_amdgcn_global_load_lds(
        (const __attribute__((address_space(1))) void*)g,
        (__attribute__((address_space(3))) void*)l, 16, 0, 0);
}

__global__ __launch_bounds__(256) void k_gemm_mfma(
    const f16* __restrict__ xHi,  const f16* __restrict__ xLo,
    const f16* __restrict__ semHi, const f16* __restrict__ semLo,
    const f16* __restrict__ lrnHi, const f16* __restrict__ lrnLo,
    const float* __restrict__ invnx, const float* __restrict__ invnb,
    float* __restrict__ logits, unsigned long long* __restrict__ keys)
{
    // HI-only LDS tiles, double-buffered: [2][128 rows][BK=32 f16] = 8KB each.
    __shared__ __align__(16) f16 sA[2][BM * BK];
    __shared__ __align__(16) f16 sB[2][BN * BK];

    const int t    = threadIdx.x;
    const int lane = t & 63;
    const int wid  = t >> 6;              // 4 waves, 2x2 over 128x128
    const int row0 = blockIdx.x * BM;
    const int col0 = blockIdx.y * BN;
    const int wm   = (wid >> 1) * 64;
    const int wn   = (wid & 1) * 64;

    // N_SEM % BN == 0, so each block's column tile is purely sem or purely lrn.
    const f16* bh; const f16* blo;
    if (col0 < N_SEM) { bh = semHi + (size_t)col0 * DIM;
                        blo = semLo + (size_t)col0 * DIM; }
    else              { bh = lrnHi + (size_t)(col0 - N_SEM) * DIM;
                        blo = lrnLo + (size_t)(col0 - N_SEM) * DIM; }
    const f16* ah  = xHi + (size_t)row0 * DIM;
    const f16* alo = xLo + (size_t)row0 * DIM;

    // HI staging, pre-swizzled SOURCE (m173): LDS slot (row sr, slot t&3) gets
    // logical chunk (t&3)^((sr>>1)&3); chunk = 8 f16 = 16 B.
    const int sr = t >> 2;                       // 0..63
    const int sc = (t & 3) ^ ((sr >> 1) & 3);
    const size_t g0 = (size_t)sr * DIM + sc * 8;
    const size_t g1 = g0 + (size_t)64 * DIM;     // chunk t+256 -> row sr+64

    // Fragment geometry: lane holds m = lane&15 (fr), k = fg*8 + j.
    const int fr  = lane & 15;
    const int fg  = lane >> 4;
    const int swz = fg ^ ((fr >> 1) & 3);        // de-swizzled ds_read chunk

    // LO per-lane global fragment bases (read straight from global, L2-hot).
    const f16* aLb = alo + (size_t)(wm + fr) * DIM + fg * 8;
    const f16* bLb = blo + (size_t)(wn + fr) * DIM + fg * 8;

    f32x4 acc[4][4];
    #pragma unroll
    for (int i = 0; i < 4; ++i)
        #pragma unroll
        for (int j = 0; j < 4; ++j) acc[i][j] = (f32x4)0.f;

#define STAGE(b, k0) do { \
        gload16(ah + g0 + (k0), &sA[b][t * 8]); \
        gload16(ah + g1 + (k0), &sA[b][t * 8 + 2048]); \
        gload16(bh + g0 + (k0), &sB[b][t * 8]); \
        gload16(bh + g1 + (k0), &sB[b][t * 8 + 2048]); \
    } while (0)

    // prologue: stage tile 0, drain, barrier
    STAGE(0, 0);
    asm volatile("s_waitcnt vmcnt(0)" ::: "memory");
    __builtin_amdgcn_s_barrier();

    int cur = 0;
    #pragma unroll 1
    for (int k0 = 0; k0 < DIM; k0 += BK) {
        // LO fragments for THIS K-step: direct global loads into registers
        // (consumed by the HL/LH MFMAs ~40 MFMA-issues later).
        f16x8 aL[4], bL[4];
        #pragma unroll
        for (int f = 0; f < 4; ++f) {
            aL[f] = *(const f16x8*)(aLb + (size_t)f * 16 * DIM + k0);
            bL[f] = *(const f16x8*)(bLb + (size_t)f * 16 * DIM + k0);
        }
        // prefetch NEXT K-step's HI tiles into the other buffer
        if (k0 + BK < DIM) STAGE(cur ^ 1, k0 + BK);

        // HI fragments from LDS (swizzled addresses)
        f16x8 aH[4], bH[4];
        #pragma unroll
        for (int f = 0; f < 4; ++f) {
            aH[f] = *(const f16x8*)(&sA[cur][(wm + f * 16 + fr) * BK + swz * 8]);
            bH[f] = *(const f16x8*)(&sB[cur][(wn + f * 16 + fr) * BK + swz * 8]);
        }
        // HH first (LDS deps only), then cross terms (register-load deps)
        #pragma unroll
        for (int i = 0; i < 4; ++i)
            #pragma unroll
            for (int j = 0; j < 4; ++j)
                acc[i][j] = __builtin_amdgcn_mfma_f32_16x16x32_f16(aH[i], bH[j], acc[i][j], 0, 0, 0);
        #pragma unroll
        for (int i = 0; i < 4; ++i)
            #pragma unroll
            for (int j = 0; j < 4; ++j) {
                acc[i][j] = __builtin_amdgcn_mfma_f32_16x16x32_f16(aH[i], bL[j], acc[i][j], 0, 0, 0);
                acc[i][j] = __builtin_amdgcn_mfma_f32_16x16x32_f16(aL[i], bH[j], acc[i][j], 0, 0, 0);
            }

        // one drain+barrier per K-step: prefetch was issued a full compute
        // phase ago, so the vmcnt(0) is (mostly) free.
        asm volatile("s_waitcnt vmcnt(0)" ::: "memory");
        __builtin_amdgcn_s_barrier();
        cur ^= 1;
    }
#undef STAGE

    // epilogue: scale by invnx*invnb, store f32 logits, per-row packed argmax.
    // C/D layout (m89/m91-verified): col = lane&15 (fr), row = fg*4 + reg.
    float ibv[4];
    #pragma unroll
    for (int fn = 0; fn < 4; ++fn) ibv[fn] = invnb[col0 + wn + fn * 16 + fr];

    #pragma unroll
    for (int fm = 0; fm < 4; ++fm) {
        #pragma unroll
        for (int reg = 0; reg < 4; ++reg) {
            const int row = row0 + wm + fm * 16 + fg * 4 + reg;
            const float ia = invnx[row];
            float best = -3.4e38f; int bcol = 0;
            float* dst = logits + (size_t)row * N_CODE + col0 + wn + fr;
            #pragma unroll
            for (int fn = 0; fn < 4; ++fn) {
                float v = acc[fm][fn][reg] * (ia * ibv[fn]);
                dst[fn * 16] = v;
                int c = col0 + wn + fn * 16 + fr;
                if (v > best) { best = v; bcol = c; }
            }
            // reduce (best,bcol) across the 16 fr-lanes of this row
            #pragma unroll
            for (int off = 8; off > 0; off >>= 1) {
                float ov = __shfl_xor(best, off);
                int   oc = __shfl_xor(bcol, off);
                if (ov > best || (ov == best && oc < bcol)) { best = ov; bcol = oc; }
            }
            if (fr == 0) {
                unsigned int u = __float_as_uint(best);
                unsigned int s = (u & 0x80000000u) ? ~u : (u | 0x80000000u);
                unsigned long long key = ((unsigned long long)s << 14) |
                                         (unsigned long long)(16383 - bcol);
                atomicMax(keys + row, key);
            }
        }
    }
}

// ---- K3: per-token gather + cos-sim; per-token loss to ws (NO global atomics) ----
__global__ __launch_bounds__(256) void k_epilogue(
    const float* __restrict__ X,
    const float* __restrict__ SEM,
    const float* __restrict__ LRN,
    const float* __restrict__ invnx,
    const float* __restrict__ invnb,
    const unsigned long long* __restrict__ keys,
    float* __restrict__ o_idx,
    float* __restrict__ o_zq,
    float* __restrict__ o_zst,
    float* __restrict__ perTok)
{
    const int tok = blockIdx.x;
    const int t = threadIdx.x;
    const int col = 16383 - (int)(keys[tok] & 16383ULL);
    const float ix = invnx[tok];
    const float ib = invnb[col];
    const float* crow = (col < N_SEM) ? (SEM + (size_t)col * DIM)
                                      : (LRN + (size_t)(col - N_SEM) * DIM);

    float4 xr = ((const float4*)(X + (size_t)tok * DIM))[t];
    float4 cr = ((const float4*)crow)[t];
    float4 xv; xv.x = xr.x*ix; xv.y = xr.y*ix; xv.z = xr.z*ix; xv.w = xr.w*ix;
    float4 zv; zv.x = cr.x*ib; zv.y = cr.y*ib; zv.z = cr.z*ib; zv.w = cr.w*ib;

    float d  = xv.x*zv.x + xv.y*zv.y + xv.z*zv.z + xv.w*zv.w;
    float nx = xv.x*xv.x + xv.y*xv.y + xv.z*xv.z + xv.w*xv.w;
    float nz = zv.x*zv.x + zv.y*zv.y + zv.z*zv.z + zv.w*zv.w;
    #pragma unroll
    for (int off = 32; off > 0; off >>= 1) {
        d  += __shfl_xor(d, off);
        nx += __shfl_xor(nx, off);
        nz += __shfl_xor(nz, off);
    }
    __shared__ float rd[4], rx[4], rz[4];
    if ((t & 63) == 0) { rd[t>>6] = d; rx[t>>6] = nx; rz[t>>6] = nz; }
    __syncthreads();

    float4 zs;
    zs.x = xv.x + (zv.x - xv.x);
    zs.y = xv.y + (zv.y - xv.y);
    zs.z = xv.z + (zv.z - xv.z);
    zs.w = xv.w + (zv.w - xv.w);
    ((float4*)o_zq)[(size_t)tok * 256 + t] = zv;
    ((float4*)o_zst)[(size_t)tok * 256 + t] = zs;

    if (t == 0) {
        float D  = rd[0]+rd[1]+rd[2]+rd[3];
        float NX = rx[0]+rx[1]+rx[2]+rx[3];
        float NZ = rz[0]+rz[1]+rz[2]+rz[3];
        float cs = D / (fmaxf(sqrtf(NX), 1e-8f) * fmaxf(sqrtf(NZ), 1e-8f));
        o_idx[tok]  = (float)col;
        perTok[tok] = 1.f - cs;
    }
}

// ---- K4: single-block reduction of per-token losses + finalize scalars ----
__global__ __launch_bounds__(256) void k_final(
    const float* __restrict__ perTok,
    const float* __restrict__ o_idx,
    float* __restrict__ o_scal)
{
    const int t = threadIdx.x;
    float cs = 0.f, vs = 0.f, vc = 0.f;
    for (int i = t; i < N_TOK; i += 256) {
        float p = perTok[i];
        cs += p;
        if (o_idx[i] >= (float)N_SEM) { vs += p; vc += 1.f; }
    }
    #pragma unroll
    for (int off = 32; off > 0; off >>= 1) {
        cs += __shfl_xor(cs, off);
        vs += __shfl_xor(vs, off);
        vc += __shfl_xor(vc, off);
    }
    __shared__ float r0[4], r1[4], r2[4];
    if ((t & 63) == 0) { r0[t>>6] = cs; r1[t>>6] = vs; r2[t>>6] = vc; }
    __syncthreads();
    if (t == 0) {
        float C = r0[0]+r0[1]+r0[2]+r0[3];
        float V = r1[0]+r1[1]+r1[2]+r1[3];
        float K = r2[0]+r2[1]+r2[2]+r2[3];
        float commit = C / (float)N_TOK;
        float vq     = V / (K + 1e-6f);
        o_scal[0] = vq;
        o_scal[1] = commit;
        o_scal[2] = vq + 0.25f * commit;
    }
}

extern "C" void kernel_launch(void* const* d_in, const int* in_sizes, int n_in,
                              void* d_out, int out_size, void* d_ws, size_t ws_size,
                              hipStream_t stream) {
    const float* x   = (const float*)d_in[0];   // [8192,1024] fp32
    const float* sem = (const float*)d_in[1];   // [8192,1024] fp32
    const float* lrn = (const float*)d_in[2];   // [128,1024]  fp32

    // ws: invnx[8192] | invnb[8320] | keys[8192] u64 | perTok[8192] | lrn hi/lo
    float* invnx = (float*)d_ws;
    float* invnb = invnx + N_TOK;
    unsigned long long* keys = (unsigned long long*)(invnb + N_CODE); // 8-aligned
    float* perTok = (float*)(keys + N_TOK);
    f16* lrnHi = (f16*)(perTok + N_TOK);        // 16-aligned
    f16* lrnLo = lrnHi + (size_t)N_LEARN * DIM;

    float* out      = (float*)d_out;
    float* o_logits = out;                                  // 68,157,440 f32
    float* o_idx    = o_logits + (size_t)N_TOK * N_CODE;    // 8,192
    float* o_zq     = o_idx + N_TOK;                        // 8,388,608
    float* o_zst    = o_zq + (size_t)N_TOK * DIM;           // 8,388,608
    float* o_scal   = o_zst + (size_t)N_TOK * DIM;          // 3

    // split scratch aliased onto z_q / z_q_st (overwritten later by k_epilogue)
    f16* xHi   = (f16*)o_zq;                    // 8192*1024 f16
    f16* xLo   = xHi + (size_t)N_TOK * DIM;     //  = exactly o_zq's 33.55 MB
    f16* semHi = (f16*)o_zst;
    f16* semLo = semHi + (size_t)N_SEM * DIM;   //  = exactly o_zst's 33.55 MB

    k_prep<<<N_TOK + N_SEM + N_LEARN, 256, 0, stream>>>(
        x, invnx, xHi, xLo, sem, invnb, semHi, semLo, lrn, lrnHi, lrnLo, keys);

    dim3 g2(N_TOK / BM, N_CODE / BN);   // 64 x 65
    k_gemm_mfma<<<g2, 256, 0, stream>>>(xHi, xLo, semHi, semLo, lrnHi, lrnLo,
                                        invnx, invnb, o_logits, keys);

    k_epilogue<<<N_TOK, 256, 0, stream>>>(x, sem, lrn, invnx, invnb, keys,
                                          o_idx, o_zq, o_zst, perTok);
    k_final<<<1, 256, 0, stream>>>(perTok, o_idx, o_scal);
}

// Round 4
// 877.283 us; speedup vs baseline: 1.1456x; 1.1456x over previous
//
#include <hip/hip_runtime.h>
#include <stdint.h>

// HybridCodebook forward, MFMA edition, R4.
//   xn = normalize(x); cb = [normalize(sem); normalize(learn)]
//   logits = xn @ cb^T ; indices = argmax ; z_q = cb[indices]; losses.
// Outputs (f32, flat): logits [8192*8320], indices [8192], z_q [8192*1024],
//   z_q_st [8192*1024], vq_loss, commitment_loss, quant_loss.
//
// R4 vs R3 (R3 REGRESSED 708 us: LO-from-global added 126MB FETCH + mid-loop
// VMEM latency on the MFMA dep chain; MfmaUtil 25%, VALUBusy 14%):
//  - REVERT to R2's all-LDS operand staging (verified swizzle, 0 conflicts).
//  - 2-phase prefetch (T3-minimum): ALL FOUR arrays (Ah,Al,Bh,Bl) double-
//    buffered in LDS (64 KB -> 2 blocks/CU cap; R2 measured ~1.7 anyway).
//    STAGE(next buf) issued BEFORE compute(cur); ONE __syncthreads() per
//    K-step AFTER the 48-MFMA cluster -> the 8 global_load_lds drain under
//    ~470 cy/SIMD of MFMA instead of stalling the wavefront immediately.
//  - T1 XCD-chunked blockIdx swizzle (4160%8==0, bijective): each XCD keeps
//    its ~8 col-tiles' B panel (~4MB) L2-resident instead of 8x refetch.
//  - T5 setprio(1) around MFMA cluster (free; likely null at 2-phase).
//
// fp16 2-split numerics (hi+lo, drop lo*lo): absmax 4.88e-4 passing since R1.
// Split staging aliases output buffer: x hi/lo fills o_zq exactly, sem hi/lo
// fills o_zst exactly; both overwritten only by k_epilogue AFTER the GEMM.

#define N_TOK   8192
#define DIM     1024
#define N_SEM   8192
#define N_LEARN 128
#define N_CODE  (N_SEM + N_LEARN)   // 8320

typedef _Float16 f16;
typedef _Float16 f16x4 __attribute__((ext_vector_type(4)));
typedef _Float16 f16x8 __attribute__((ext_vector_type(8)));
typedef float    f32x4 __attribute__((ext_vector_type(4)));

// ---- K1: per-row inverse L2 norm + fp16 hi/lo split write (x|sem|lrn fused),
//          plus keys zeroing (ws is poisoned 0xAA) ----
__global__ __launch_bounds__(256) void k_prep(
    const float* __restrict__ x,   float* __restrict__ invnx,
    f16* __restrict__ xHi,  f16* __restrict__ xLo,
    const float* __restrict__ sem, float* __restrict__ invnb,
    f16* __restrict__ semHi, f16* __restrict__ semLo,
    const float* __restrict__ lrn,
    f16* __restrict__ lrnHi, f16* __restrict__ lrnLo,
    unsigned long long* __restrict__ keys)
{
    const int b = blockIdx.x;
    const int t = threadIdx.x;
    const float* in; float* invn; f16* hi; f16* lo; int row;
    if (b < N_TOK) {
        row = b; in = x; invn = invnx; hi = xHi; lo = xLo;
        if (t == 0) keys[row] = 0ULL;
    } else if (b < N_TOK + N_SEM) {
        row = b - N_TOK; in = sem; invn = invnb; hi = semHi; lo = semLo;
    } else {
        row = b - N_TOK - N_SEM; in = lrn; invn = invnb + N_SEM;
        hi = lrnHi; lo = lrnLo;
    }

    float4 v = ((const float4*)(in + (size_t)row * DIM))[t];
    float ss = v.x*v.x + v.y*v.y + v.z*v.z + v.w*v.w;
    #pragma unroll
    for (int off = 32; off > 0; off >>= 1) ss += __shfl_xor(ss, off);
    __shared__ float red[4];
    if ((t & 63) == 0) red[t >> 6] = ss;

    f16 h0 = (f16)v.x, h1 = (f16)v.y, h2 = (f16)v.z, h3 = (f16)v.w;
    f16x4 hv = {h0, h1, h2, h3};
    f16x4 lv = {(f16)(v.x - (float)h0), (f16)(v.y - (float)h1),
                (f16)(v.z - (float)h2), (f16)(v.w - (float)h3)};
    ((f16x4*)(hi + (size_t)row * DIM))[t] = hv;
    ((f16x4*)(lo + (size_t)row * DIM))[t] = lv;

    __syncthreads();
    if (t == 0) {
        float tot = red[0] + red[1] + red[2] + red[3];
        invn[row] = 1.f / fmaxf(sqrtf(tot), 1e-8f);
    }
}

// ---- K2: fp16-split MFMA GEMM + scaled f32 logits store + packed argmax ----
#define BM 128
#define BN 128
#define BK 32

__device__ __forceinline__ void gload16(const void* g, void* l) {
    __builtin_amdgcn_global_load_lds(
        (const __attribute__((address_space(1))) void*)g,
        (__attribute__((address_space(3))) void*)l, 16, 0, 0);
}

__global__ __launch_bounds__(256) void k_gemm_mfma(
    const f16* __restrict__ xHi,  const f16* __restrict__ xLo,
    const f16* __restrict__ semHi, const f16* __restrict__ semLo,
    const f16* __restrict__ lrnHi, const f16* __restrict__ lrnLo,
    const float* __restrict__ invnx, const float* __restrict__ invnb,
    float* __restrict__ logits, unsigned long long* __restrict__ keys)
{
    // All four operand tiles, double-buffered: [2][128 rows][BK=32 f16] = 64 KB.
    __shared__ __align__(16) f16 sAh[2][BM * BK];
    __shared__ __align__(16) f16 sAl[2][BM * BK];
    __shared__ __align__(16) f16 sBh[2][BN * BK];
    __shared__ __align__(16) f16 sBl[2][BN * BK];

    const int t    = threadIdx.x;
    const int lane = t & 63;
    const int wid  = t >> 6;              // 4 waves, 2x2 over 128x128
    const int wm   = (wid >> 1) * 64;
    const int wn   = (wid & 1) * 64;

    // T1: XCD-chunked bijective swizzle over the 64x65=4160 grid (4160%8==0).
    // Consecutive dispatch slots round-robin XCDs; chunked remap gives each
    // XCD a contiguous run of 520 slots = ~8 col-tiles whose B panels stay
    // L2-resident.
    const int nwg  = (N_TOK / BM) * (N_CODE / BN);          // 4160
    const int bid  = blockIdx.y * (N_TOK / BM) + blockIdx.x;
    const int swzb = (bid % 8) * (nwg / 8) + bid / 8;
    const int rb   = swzb % (N_TOK / BM);
    const int cb   = swzb / (N_TOK / BM);
    const int row0 = rb * BM;
    const int col0 = cb * BN;

    // N_SEM % BN == 0, so each block's column tile is purely sem or purely lrn.
    const f16* bh; const f16* blo;
    if (col0 < N_SEM) { bh = semHi + (size_t)col0 * DIM;
                        blo = semLo + (size_t)col0 * DIM; }
    else              { bh = lrnHi + (size_t)(col0 - N_SEM) * DIM;
                        blo = lrnLo + (size_t)(col0 - N_SEM) * DIM; }
    const f16* ah  = xHi + (size_t)row0 * DIM;
    const f16* alo = xLo + (size_t)row0 * DIM;

    // Staging, pre-swizzled SOURCE (m173): LDS slot (row sr, slot t&3) gets
    // logical chunk (t&3)^((sr>>1)&3); chunk = 8 f16 = 16 B.
    const int sr = t >> 2;                       // 0..63
    const int sc = (t & 3) ^ ((sr >> 1) & 3);
    const size_t g0 = (size_t)sr * DIM + sc * 8;
    const size_t g1 = g0 + (size_t)64 * DIM;     // chunk t+256 -> row sr+64

    // Fragment geometry: lane holds m = lane&15 (fr), k = fg*8 + j.
    const int fr  = lane & 15;
    const int fg  = lane >> 4;
    const int swz = fg ^ ((fr >> 1) & 3);        // de-swizzled ds_read chunk

    f32x4 acc[4][4];
    #pragma unroll
    for (int i = 0; i < 4; ++i)
        #pragma unroll
        for (int j = 0; j < 4; ++j) acc[i][j] = (f32x4)0.f;

#define STAGE(bf, k0) do { \
        gload16(ah  + g0 + (k0), &sAh[bf][t * 8]); \
        gload16(ah  + g1 + (k0), &sAh[bf][t * 8 + 2048]); \
        gload16(alo + g0 + (k0), &sAl[bf][t * 8]); \
        gload16(alo + g1 + (k0), &sAl[bf][t * 8 + 2048]); \
        gload16(bh  + g0 + (k0), &sBh[bf][t * 8]); \
        gload16(bh  + g1 + (k0), &sBh[bf][t * 8 + 2048]); \
        gload16(blo + g0 + (k0), &sBl[bf][t * 8]); \
        gload16(blo + g1 + (k0), &sBl[bf][t * 8 + 2048]); \
    } while (0)

    // prologue: stage tile 0 into buf 0, full drain
    STAGE(0, 0);
    __syncthreads();

    int cur = 0;
    #pragma unroll 1
    for (int k0 = 0; k0 < DIM; k0 += BK) {
        // 2-phase: issue next tile's staging FIRST (drains at end-of-iter
        // syncthreads, a full MFMA phase from now).
        if (k0 + BK < DIM) STAGE(cur ^ 1, k0 + BK);

        // fragments from LDS (swizzled addresses)
        f16x8 aH[4], aL[4], bH[4], bL[4];
        #pragma unroll
        for (int f = 0; f < 4; ++f) {
            aH[f] = *(const f16x8*)(&sAh[cur][(wm + f * 16 + fr) * BK + swz * 8]);
            aL[f] = *(const f16x8*)(&sAl[cur][(wm + f * 16 + fr) * BK + swz * 8]);
            bH[f] = *(const f16x8*)(&sBh[cur][(wn + f * 16 + fr) * BK + swz * 8]);
            bL[f] = *(const f16x8*)(&sBl[cur][(wn + f * 16 + fr) * BK + swz * 8]);
        }
        __builtin_amdgcn_s_setprio(1);
        #pragma unroll
        for (int i = 0; i < 4; ++i)
            #pragma unroll
            for (int j = 0; j < 4; ++j) {
                acc[i][j] = __builtin_amdgcn_mfma_f32_16x16x32_f16(aH[i], bH[j], acc[i][j], 0, 0, 0);
                acc[i][j] = __builtin_amdgcn_mfma_f32_16x16x32_f16(aH[i], bL[j], acc[i][j], 0, 0, 0);
                acc[i][j] = __builtin_amdgcn_mfma_f32_16x16x32_f16(aL[i], bH[j], acc[i][j], 0, 0, 0);
            }
        __builtin_amdgcn_s_setprio(0);

        // single drain per K-step: vmcnt(0)+lgkmcnt(0)+barrier, AFTER compute.
        __syncthreads();
        cur ^= 1;
    }
#undef STAGE

    // epilogue: scale by invnx*invnb, store f32 logits, per-row packed argmax.
    // C/D layout (m89/m91-verified): col = lane&15 (fr), row = fg*4 + reg.
    float ibv[4];
    #pragma unroll
    for (int fn = 0; fn < 4; ++fn) ibv[fn] = invnb[col0 + wn + fn * 16 + fr];

    #pragma unroll
    for (int fm = 0; fm < 4; ++fm) {
        #pragma unroll
        for (int reg = 0; reg < 4; ++reg) {
            const int row = row0 + wm + fm * 16 + fg * 4 + reg;
            const float ia = invnx[row];
            float best = -3.4e38f; int bcol = 0;
            float* dst = logits + (size_t)row * N_CODE + col0 + wn + fr;
            #pragma unroll
            for (int fn = 0; fn < 4; ++fn) {
                float v = acc[fm][fn][reg] * (ia * ibv[fn]);
                dst[fn * 16] = v;
                int c = col0 + wn + fn * 16 + fr;
                if (v > best) { best = v; bcol = c; }
            }
            // reduce (best,bcol) across the 16 fr-lanes of this row
            #pragma unroll
            for (int off = 8; off > 0; off >>= 1) {
                float ov = __shfl_xor(best, off);
                int   oc = __shfl_xor(bcol, off);
                if (ov > best || (ov == best && oc < bcol)) { best = ov; bcol = oc; }
            }
            if (fr == 0) {
                unsigned int u = __float_as_uint(best);
                unsigned int s = (u & 0x80000000u) ? ~u : (u | 0x80000000u);
                unsigned long long key = ((unsigned long long)s << 14) |
                                         (unsigned long long)(16383 - bcol);
                atomicMax(keys + row, key);
            }
        }
    }
}

// ---- K3: per-token gather + cos-sim; per-token loss to ws (NO global atomics) ----
__global__ __launch_bounds__(256) void k_epilogue(
    const float* __restrict__ X,
    const float* __restrict__ SEM,
    const float* __restrict__ LRN,
    const float* __restrict__ invnx,
    const float* __restrict__ invnb,
    const unsigned long long* __restrict__ keys,
    float* __restrict__ o_idx,
    float* __restrict__ o_zq,
    float* __restrict__ o_zst,
    float* __restrict__ perTok)
{
    const int tok = blockIdx.x;
    const int t = threadIdx.x;
    const int col = 16383 - (int)(keys[tok] & 16383ULL);
    const float ix = invnx[tok];
    const float ib = invnb[col];
    const float* crow = (col < N_SEM) ? (SEM + (size_t)col * DIM)
                                      : (LRN + (size_t)(col - N_SEM) * DIM);

    float4 xr = ((const float4*)(X + (size_t)tok * DIM))[t];
    float4 cr = ((const float4*)crow)[t];
    float4 xv; xv.x = xr.x*ix; xv.y = xr.y*ix; xv.z = xr.z*ix; xv.w = xr.w*ix;
    float4 zv; zv.x = cr.x*ib; zv.y = cr.y*ib; zv.z = cr.z*ib; zv.w = cr.w*ib;

    float d  = xv.x*zv.x + xv.y*zv.y + xv.z*zv.z + xv.w*zv.w;
    float nx = xv.x*xv.x + xv.y*xv.y + xv.z*xv.z + xv.w*xv.w;
    float nz = zv.x*zv.x + zv.y*zv.y + zv.z*zv.z + zv.w*zv.w;
    #pragma unroll
    for (int off = 32; off > 0; off >>= 1) {
        d  += __shfl_xor(d, off);
        nx += __shfl_xor(nx, off);
        nz += __shfl_xor(nz, off);
    }
    __shared__ float rd[4], rx[4], rz[4];
    if ((t & 63) == 0) { rd[t>>6] = d; rx[t>>6] = nx; rz[t>>6] = nz; }
    __syncthreads();

    float4 zs;
    zs.x = xv.x + (zv.x - xv.x);
    zs.y = xv.y + (zv.y - xv.y);
    zs.z = xv.z + (zv.z - xv.z);
    zs.w = xv.w + (zv.w - xv.w);
    ((float4*)o_zq)[(size_t)tok * 256 + t] = zv;
    ((float4*)o_zst)[(size_t)tok * 256 + t] = zs;

    if (t == 0) {
        float D  = rd[0]+rd[1]+rd[2]+rd[3];
        float NX = rx[0]+rx[1]+rx[2]+rx[3];
        float NZ = rz[0]+rz[1]+rz[2]+rz[3];
        float cs = D / (fmaxf(sqrtf(NX), 1e-8f) * fmaxf(sqrtf(NZ), 1e-8f));
        o_idx[tok]  = (float)col;
        perTok[tok] = 1.f - cs;
    }
}

// ---- K4: single-block reduction of per-token losses + finalize scalars ----
__global__ __launch_bounds__(256) void k_final(
    const float* __restrict__ perTok,
    const float* __restrict__ o_idx,
    float* __restrict__ o_scal)
{
    const int t = threadIdx.x;
    float cs = 0.f, vs = 0.f, vc = 0.f;
    for (int i = t; i < N_TOK; i += 256) {
        float p = perTok[i];
        cs += p;
        if (o_idx[i] >= (float)N_SEM) { vs += p; vc += 1.f; }
    }
    #pragma unroll
    for (int off = 32; off > 0; off >>= 1) {
        cs += __shfl_xor(cs, off);
        vs += __shfl_xor(vs, off);
        vc += __shfl_xor(vc, off);
    }
    __shared__ float r0[4], r1[4], r2[4];
    if ((t & 63) == 0) { r0[t>>6] = cs; r1[t>>6] = vs; r2[t>>6] = vc; }
    __syncthreads();
    if (t == 0) {
        float C = r0[0]+r0[1]+r0[2]+r0[3];
        float V = r1[0]+r1[1]+r1[2]+r1[3];
        float K = r2[0]+r2[1]+r2[2]+r2[3];
        float commit = C / (float)N_TOK;
        float vq     = V / (K + 1e-6f);
        o_scal[0] = vq;
        o_scal[1] = commit;
        o_scal[2] = vq + 0.25f * commit;
    }
}

extern "C" void kernel_launch(void* const* d_in, const int* in_sizes, int n_in,
                              void* d_out, int out_size, void* d_ws, size_t ws_size,
                              hipStream_t stream) {
    const float* x   = (const float*)d_in[0];   // [8192,1024] fp32
    const float* sem = (const float*)d_in[1];   // [8192,1024] fp32
    const float* lrn = (const float*)d_in[2];   // [128,1024]  fp32

    // ws: invnx[8192] | invnb[8320] | keys[8192] u64 | perTok[8192] | lrn hi/lo
    float* invnx = (float*)d_ws;
    float* invnb = invnx + N_TOK;
    unsigned long long* keys = (unsigned long long*)(invnb + N_CODE); // 8-aligned
    float* perTok = (float*)(keys + N_TOK);
    f16* lrnHi = (f16*)(perTok + N_TOK);        // 16-aligned
    f16* lrnLo = lrnHi + (size_t)N_LEARN * DIM;

    float* out      = (float*)d_out;
    float* o_logits = out;                                  // 68,157,440 f32
    float* o_idx    = o_logits + (size_t)N_TOK * N_CODE;    // 8,192
    float* o_zq     = o_idx + N_TOK;                        // 8,388,608
    float* o_zst    = o_zq + (size_t)N_TOK * DIM;           // 8,388,608
    float* o_scal   = o_zst + (size_t)N_TOK * DIM;          // 3

    // split scratch aliased onto z_q / z_q_st (overwritten later by k_epilogue)
    f16* xHi   = (f16*)o_zq;                    // 8192*1024 f16
    f16* xLo   = xHi + (size_t)N_TOK * DIM;     //  = exactly o_zq's 33.55 MB
    f16* semHi = (f16*)o_zst;
    f16* semLo = semHi + (size_t)N_SEM * DIM;   //  = exactly o_zst's 33.55 MB

    k_prep<<<N_TOK + N_SEM + N_LEARN, 256, 0, stream>>>(
        x, invnx, xHi, xLo, sem, invnb, semHi, semLo, lrn, lrnHi, lrnLo, keys);

    dim3 g2(N_TOK / BM, N_CODE / BN);   // 64 x 65
    k_gemm_mfma<<<g2, 256, 0, stream>>>(xHi, xLo, semHi, semLo, lrnHi, lrnLo,
                                        invnx, invnb, o_logits, keys);

    k_epilogue<<<N_TOK, 256, 0, stream>>>(x, sem, lrn, invnx, invnb, keys,
                                          o_idx, o_zq, o_zst, perTok);
    k_final<<<1, 256, 0, stream>>>(perTok, o_idx, o_scal);
}

// Round 6
// 851.347 us; speedup vs baseline: 1.1805x; 1.0305x over previous
//
#include <hip/hip_runtime.h>
#include <stdint.h>

// HybridCodebook forward, MFMA edition, R5 (resubmit — R5 bench never ran:
// GPUAcquisitionTimeout; source re-audited, no changes).
//   xn = normalize(x); cb = [normalize(sem); normalize(learn)]
//   logits = xn @ cb^T ; indices = argmax ; z_q = cb[indices]; losses.
//
// R5 vs R4 (877 us; GEMM 552, MfmaUtil 34% == measured m97-structure ceiling,
// reproduced twice; all pipes have slack -> schedule-bound):
//  - GEMM rebuilt on the 256^2 8-phase template (T3+T4+T2+T5): 8 waves/block
//    (512 thr), BM=BN=256, BK=32, per-K-step 4 quadrant-phases of
//    {ds_read frags | 2-3 global_load_lds for next tile | barrier |
//     lgkmcnt(0) | setprio(1) | 24 MFMA | setprio(0) | barrier};
//    vmcnt(0) ONLY at K-step boundary (T4: staged loads span 1-4 phases).
//    LDS = 4 arrays x dbuf x 16KB = 128 KB, 1 block/CU.
//  - T1 XCD swizzle REMOVED (R4 measured: FETCH 281MB -> 1.1GB, no time delta).
//  - Tail col-tile (8320 = 32*256 + 128): staging rows clamped (valid mem),
//    barriers uniform; waves with wn>=128 in that tile skip stores/argmax
//    (wave-uniform predicate, applied only in the barrier-free epilogue).
//
// Numerics IDENTICAL to R1-R4 (same per-acc accumulation order) -> absmax
// must remain bit-exact 0.0004882812.

#define N_TOK   8192
#define DIM     1024
#define N_SEM   8192
#define N_LEARN 128
#define N_CODE  (N_SEM + N_LEARN)   // 8320

typedef _Float16 f16;
typedef _Float16 f16x4 __attribute__((ext_vector_type(4)));
typedef _Float16 f16x8 __attribute__((ext_vector_type(8)));
typedef float    f32x4 __attribute__((ext_vector_type(4)));

// ---- K1: per-row inverse L2 norm + fp16 hi/lo split write (x|sem|lrn fused),
//          plus keys zeroing (ws is poisoned 0xAA) ----
__global__ __launch_bounds__(256) void k_prep(
    const float* __restrict__ x,   float* __restrict__ invnx,
    f16* __restrict__ xHi,  f16* __restrict__ xLo,
    const float* __restrict__ sem, float* __restrict__ invnb,
    f16* __restrict__ semHi, f16* __restrict__ semLo,
    const float* __restrict__ lrn,
    f16* __restrict__ lrnHi, f16* __restrict__ lrnLo,
    unsigned long long* __restrict__ keys)
{
    const int b = blockIdx.x;
    const int t = threadIdx.x;
    const float* in; float* invn; f16* hi; f16* lo; int row;
    if (b < N_TOK) {
        row = b; in = x; invn = invnx; hi = xHi; lo = xLo;
        if (t == 0) keys[row] = 0ULL;
    } else if (b < N_TOK + N_SEM) {
        row = b - N_TOK; in = sem; invn = invnb; hi = semHi; lo = semLo;
    } else {
        row = b - N_TOK - N_SEM; in = lrn; invn = invnb + N_SEM;
        hi = lrnHi; lo = lrnLo;
    }

    float4 v = ((const float4*)(in + (size_t)row * DIM))[t];
    float ss = v.x*v.x + v.y*v.y + v.z*v.z + v.w*v.w;
    #pragma unroll
    for (int off = 32; off > 0; off >>= 1) ss += __shfl_xor(ss, off);
    __shared__ float red[4];
    if ((t & 63) == 0) red[t >> 6] = ss;

    f16 h0 = (f16)v.x, h1 = (f16)v.y, h2 = (f16)v.z, h3 = (f16)v.w;
    f16x4 hv = {h0, h1, h2, h3};
    f16x4 lv = {(f16)(v.x - (float)h0), (f16)(v.y - (float)h1),
                (f16)(v.z - (float)h2), (f16)(v.w - (float)h3)};
    ((f16x4*)(hi + (size_t)row * DIM))[t] = hv;
    ((f16x4*)(lo + (size_t)row * DIM))[t] = lv;

    __syncthreads();
    if (t == 0) {
        float tot = red[0] + red[1] + red[2] + red[3];
        invn[row] = 1.f / fmaxf(sqrtf(tot), 1e-8f);
    }
}

// ---- K2: fp16-split MFMA GEMM, 256^2 tile, 8-phase schedule ----
#define BM 256
#define BN 256
#define BK 32

__device__ __forceinline__ void gload16(const void* g, void* l) {
    __builtin_amdgcn_global_load_lds(
        (const __attribute__((address_space(1))) void*)g,
        (__attribute__((address_space(3))) void*)l, 16, 0, 0);
}

__global__ __launch_bounds__(512, 2) void k_gemm_mfma(
    const f16* __restrict__ xHi,  const f16* __restrict__ xLo,
    const f16* __restrict__ semHi, const f16* __restrict__ semLo,
    const f16* __restrict__ lrnHi, const f16* __restrict__ lrnLo,
    const float* __restrict__ invnx, const float* __restrict__ invnb,
    float* __restrict__ logits, unsigned long long* __restrict__ keys)
{
    // [2 dbuf][256 rows][BK=32 f16] per operand array; 4 arrays = 128 KB.
    __shared__ __align__(16) f16 sAh[2][BM * BK];
    __shared__ __align__(16) f16 sAl[2][BM * BK];
    __shared__ __align__(16) f16 sBh[2][BN * BK];
    __shared__ __align__(16) f16 sBl[2][BN * BK];

    const int t    = threadIdx.x;
    const int lane = t & 63;
    const int wid  = t >> 6;               // 8 waves: 2 (M) x 4 (N)
    const int wm   = (wid >> 2) * 128;     // 128-row band per wave
    const int wn   = (wid & 3) * 64;       // 64-col band per wave
    const int row0 = blockIdx.x * BM;
    const int col0 = blockIdx.y * BN;

    // Column tile is purely sem (by<32) or purely learnable (by==32).
    const f16 *bhB, *blB; int bbase, brMax;
    if (col0 < N_SEM) { bhB = semHi; blB = semLo; bbase = col0; brMax = 255; }
    else              { bhB = lrnHi; blB = lrnLo; bbase = 0;    brMax = 127; }

    // Staging geometry: 512 threads x 16 B = 8 KB per gload-set = half of one
    // 256x32 array. Source pre-swizzle (m173): slot (row, t&3) holds logical
    // chunk (t&3)^((row>>1)&3); second half rows (128+srow) keep the same
    // swizzle bits since 128>>1 ≡ 0 (mod 4).
    const int srow = t >> 2;                               // 0..127
    const int sc8  = (((t & 3) ^ ((srow >> 1) & 3))) * 8;
    const int br1  = (128 + srow > brMax) ? brMax : (128 + srow);
    const f16* aSh0 = xHi + (size_t)(row0 + srow) * DIM + sc8;
    const f16* aSh1 = aSh0 + (size_t)128 * DIM;
    const f16* aSl0 = xLo + (size_t)(row0 + srow) * DIM + sc8;
    const f16* aSl1 = aSl0 + (size_t)128 * DIM;
    const f16* bSh0 = bhB + (size_t)(bbase + srow) * DIM + sc8;
    const f16* bSh1 = bhB + (size_t)(bbase + br1) * DIM + sc8;
    const f16* bSl0 = blB + (size_t)(bbase + srow) * DIM + sc8;
    const f16* bSl1 = blB + (size_t)(bbase + br1) * DIM + sc8;

    // Fragment geometry (16x16x32): m = lane&15 (fr), k = fg*8 + j.
    const int fr   = lane & 15;
    const int fg   = lane >> 4;
    const int swz8 = (fg ^ ((fr >> 1) & 3)) * 8;   // de-swizzled chunk offset

    f32x4 acc[8][4];
    #pragma unroll
    for (int i = 0; i < 8; ++i)
        #pragma unroll
        for (int j = 0; j < 4; ++j) acc[i][j] = (f32x4)0.f;

    f16x8 aH[4], aL[4], bH[2][2], bL[2][2];

#define READ_A(MH) do { \
    _Pragma("unroll") \
    for (int f = 0; f < 4; ++f) { \
        const int r = wm + (MH)*64 + f*16 + fr; \
        aH[f] = *(const f16x8*)(&sAh[cur][r*32 + swz8]); \
        aL[f] = *(const f16x8*)(&sAl[cur][r*32 + swz8]); \
    } } while (0)

#define READ_B(NH) do { \
    _Pragma("unroll") \
    for (int g = 0; g < 2; ++g) { \
        const int r = wn + (NH)*32 + g*16 + fr; \
        bH[NH][g] = *(const f16x8*)(&sBh[cur][r*32 + swz8]); \
        bL[NH][g] = *(const f16x8*)(&sBl[cur][r*32 + swz8]); \
    } } while (0)

#define PH_MFMA(MH, NH) do { \
    _Pragma("unroll") \
    for (int f = 0; f < 4; ++f) { \
        _Pragma("unroll") \
        for (int g = 0; g < 2; ++g) { \
            acc[(MH)*4+f][(NH)*2+g] = __builtin_amdgcn_mfma_f32_16x16x32_f16(aH[f], bH[NH][g], acc[(MH)*4+f][(NH)*2+g], 0, 0, 0); \
            acc[(MH)*4+f][(NH)*2+g] = __builtin_amdgcn_mfma_f32_16x16x32_f16(aH[f], bL[NH][g], acc[(MH)*4+f][(NH)*2+g], 0, 0, 0); \
            acc[(MH)*4+f][(NH)*2+g] = __builtin_amdgcn_mfma_f32_16x16x32_f16(aL[f], bH[NH][g], acc[(MH)*4+f][(NH)*2+g], 0, 0, 0); \
        } } } while (0)

#define GLD(ARR, P0, P1, BUF, kk) do { \
    gload16((P0) + (kk), &ARR[BUF][t * 8]); \
    gload16((P1) + (kk), &ARR[BUF][4096 + t * 8]); } while (0)

#define LGKM0()  asm volatile("s_waitcnt lgkmcnt(0)" ::: "memory")
#define VM0()    asm volatile("s_waitcnt vmcnt(0)" ::: "memory")
#define BAR()    __builtin_amdgcn_s_barrier()
#define PRIO(n)  __builtin_amdgcn_s_setprio(n)

    // prologue: stage tile 0 into buf 0, drain fully
    GLD(sAh, aSh0, aSh1, 0, 0);
    GLD(sAl, aSl0, aSl1, 0, 0);
    GLD(sBh, bSh0, bSh1, 0, 0);
    GLD(sBl, bSl0, bSl1, 0, 0);
    VM0();
    BAR();

    int cur = 0;
    #pragma unroll 1
    for (int k0 = 0; k0 < DIM; k0 += BK) {
        const int  k1  = k0 + BK;
        const bool pre = (k1 < DIM);
        const int  nxt = cur ^ 1;

        // PH1: a-half0 (8 ds_read) + b-half0 (4); stage Ah halves
        READ_A(0); READ_B(0);
        if (pre) GLD(sAh, aSh0, aSh1, nxt, k1);
        BAR(); LGKM0();
        PRIO(1); PH_MFMA(0, 0); PRIO(0);
        BAR();

        // PH2: b-half1 (4 ds_read); stage Al halves + Bh half0
        READ_B(1);
        if (pre) { GLD(sAl, aSl0, aSl1, nxt, k1);
                   gload16(bSh0 + k1, &sBh[nxt][t * 8]); }
        BAR(); LGKM0();
        PRIO(1); PH_MFMA(0, 1); PRIO(0);
        BAR();

        // PH3: a-half1 (8 ds_read); stage Bh half1 + Bl halves
        READ_A(1);
        if (pre) { gload16(bSh1 + k1, &sBh[nxt][4096 + t * 8]);
                   GLD(sBl, bSl0, bSl1, nxt, k1); }
        BAR(); LGKM0();
        PRIO(1); PH_MFMA(1, 0); PRIO(0);
        BAR();

        // PH4: no ds_read, no staging; MFMA then the ONLY vmcnt of the step
        PRIO(1); PH_MFMA(1, 1); PRIO(0);
        VM0();      // next tile's 8 loads had 1-3 phases to fly
        BAR();
        cur ^= 1;
    }
#undef READ_A
#undef READ_B
#undef PH_MFMA
#undef GLD

    // epilogue: scale by invnx*invnb, store f32 logits, per-row packed argmax.
    // C/D layout (verified since R1): col = lane&15 (fr), row = fg*4 + reg.
    // Tail tile: waves with cols >= N_CODE skip everything (wave-uniform,
    // barrier-free region).
    const bool wvalid = (col0 + wn + 63) < N_CODE;
    float ibv[4];
    #pragma unroll
    for (int nf = 0; nf < 4; ++nf)
        ibv[nf] = wvalid ? invnb[col0 + wn + nf * 16 + fr] : 1.f;

    if (wvalid) {
        #pragma unroll
        for (int mf = 0; mf < 8; ++mf) {
            #pragma unroll
            for (int reg = 0; reg < 4; ++reg) {
                const int row = row0 + wm + mf * 16 + fg * 4 + reg;
                const float ia = invnx[row];
                float best = -3.4e38f; int bcol = 0;
                float* dst = logits + (size_t)row * N_CODE + col0 + wn + fr;
                #pragma unroll
                for (int nf = 0; nf < 4; ++nf) {
                    float v = acc[mf][nf][reg] * (ia * ibv[nf]);
                    dst[nf * 16] = v;
                    int c = col0 + wn + nf * 16 + fr;
                    if (v > best) { best = v; bcol = c; }
                }
                #pragma unroll
                for (int off = 8; off > 0; off >>= 1) {
                    float ov = __shfl_xor(best, off);
                    int   oc = __shfl_xor(bcol, off);
                    if (ov > best || (ov == best && oc < bcol)) { best = ov; bcol = oc; }
                }
                if (fr == 0) {
                    unsigned int u = __float_as_uint(best);
                    unsigned int s = (u & 0x80000000u) ? ~u : (u | 0x80000000u);
                    unsigned long long key = ((unsigned long long)s << 14) |
                                             (unsigned long long)(16383 - bcol);
                    atomicMax(keys + row, key);
                }
            }
        }
    }
}

// ---- K3: per-token gather + cos-sim; per-token loss to ws (NO global atomics) ----
__global__ __launch_bounds__(256) void k_epilogue(
    const float* __restrict__ X,
    const float* __restrict__ SEM,
    const float* __restrict__ LRN,
    const float* __restrict__ invnx,
    const float* __restrict__ invnb,
    const unsigned long long* __restrict__ keys,
    float* __restrict__ o_idx,
    float* __restrict__ o_zq,
    float* __restrict__ o_zst,
    float* __restrict__ perTok)
{
    const int tok = blockIdx.x;
    const int t = threadIdx.x;
    const int col = 16383 - (int)(keys[tok] & 16383ULL);
    const float ix = invnx[tok];
    const float ib = invnb[col];
    const float* crow = (col < N_SEM) ? (SEM + (size_t)col * DIM)
                                      : (LRN + (size_t)(col - N_SEM) * DIM);

    float4 xr = ((const float4*)(X + (size_t)tok * DIM))[t];
    float4 cr = ((const float4*)crow)[t];
    float4 xv; xv.x = xr.x*ix; xv.y = xr.y*ix; xv.z = xr.z*ix; xv.w = xr.w*ix;
    float4 zv; zv.x = cr.x*ib; zv.y = cr.y*ib; zv.z = cr.z*ib; zv.w = cr.w*ib;

    float d  = xv.x*zv.x + xv.y*zv.y + xv.z*zv.z + xv.w*zv.w;
    float nx = xv.x*xv.x + xv.y*xv.y + xv.z*xv.z + xv.w*xv.w;
    float nz = zv.x*zv.x + zv.y*zv.y + zv.z*zv.z + zv.w*zv.w;
    #pragma unroll
    for (int off = 32; off > 0; off >>= 1) {
        d  += __shfl_xor(d, off);
        nx += __shfl_xor(nx, off);
        nz += __shfl_xor(nz, off);
    }
    __shared__ float rd[4], rx[4], rz[4];
    if ((t & 63) == 0) { rd[t>>6] = d; rx[t>>6] = nx; rz[t>>6] = nz; }
    __syncthreads();

    float4 zs;
    zs.x = xv.x + (zv.x - xv.x);
    zs.y = xv.y + (zv.y - xv.y);
    zs.z = xv.z + (zv.z - xv.z);
    zs.w = xv.w + (zv.w - xv.w);
    ((float4*)o_zq)[(size_t)tok * 256 + t] = zv;
    ((float4*)o_zst)[(size_t)tok * 256 + t] = zs;

    if (t == 0) {
        float D  = rd[0]+rd[1]+rd[2]+rd[3];
        float NX = rx[0]+rx[1]+rx[2]+rx[3];
        float NZ = rz[0]+rz[1]+rz[2]+rz[3];
        float cs = D / (fmaxf(sqrtf(NX), 1e-8f) * fmaxf(sqrtf(NZ), 1e-8f));
        o_idx[tok]  = (float)col;
        perTok[tok] = 1.f - cs;
    }
}

// ---- K4: single-block reduction of per-token losses + finalize scalars ----
__global__ __launch_bounds__(256) void k_final(
    const float* __restrict__ perTok,
    const float* __restrict__ o_idx,
    float* __restrict__ o_scal)
{
    const int t = threadIdx.x;
    float cs = 0.f, vs = 0.f, vc = 0.f;
    for (int i = t; i < N_TOK; i += 256) {
        float p = perTok[i];
        cs += p;
        if (o_idx[i] >= (float)N_SEM) { vs += p; vc += 1.f; }
    }
    #pragma unroll
    for (int off = 32; off > 0; off >>= 1) {
        cs += __shfl_xor(cs, off);
        vs += __shfl_xor(vs, off);
        vc += __shfl_xor(vc, off);
    }
    __shared__ float r0[4], r1[4], r2[4];
    if ((t & 63) == 0) { r0[t>>6] = cs; r1[t>>6] = vs; r2[t>>6] = vc; }
    __syncthreads();
    if (t == 0) {
        float C = r0[0]+r0[1]+r0[2]+r0[3];
        float V = r1[0]+r1[1]+r1[2]+r1[3];
        float K = r2[0]+r2[1]+r2[2]+r2[3];
        float commit = C / (float)N_TOK;
        float vq     = V / (K + 1e-6f);
        o_scal[0] = vq;
        o_scal[1] = commit;
        o_scal[2] = vq + 0.25f * commit;
    }
}

extern "C" void kernel_launch(void* const* d_in, const int* in_sizes, int n_in,
                              void* d_out, int out_size, void* d_ws, size_t ws_size,
                              hipStream_t stream) {
    const float* x   = (const float*)d_in[0];   // [8192,1024] fp32
    const float* sem = (const float*)d_in[1];   // [8192,1024] fp32
    const float* lrn = (const float*)d_in[2];   // [128,1024]  fp32

    // ws: invnx[8192] | invnb[8320] | keys[8192] u64 | perTok[8192] | lrn hi/lo
    float* invnx = (float*)d_ws;
    float* invnb = invnx + N_TOK;
    unsigned long long* keys = (unsigned long long*)(invnb + N_CODE); // 8-aligned
    float* perTok = (float*)(keys + N_TOK);
    f16* lrnHi = (f16*)(perTok + N_TOK);        // 16-aligned
    f16* lrnLo = lrnHi + (size_t)N_LEARN * DIM;

    float* out      = (float*)d_out;
    float* o_logits = out;                                  // 68,157,440 f32
    float* o_idx    = o_logits + (size_t)N_TOK * N_CODE;    // 8,192
    float* o_zq     = o_idx + N_TOK;                        // 8,388,608
    float* o_zst    = o_zq + (size_t)N_TOK * DIM;           // 8,388,608
    float* o_scal   = o_zst + (size_t)N_TOK * DIM;          // 3

    // split scratch aliased onto z_q / z_q_st (overwritten later by k_epilogue)
    f16* xHi   = (f16*)o_zq;                    // 8192*1024 f16
    f16* xLo   = xHi + (size_t)N_TOK * DIM;     //  = exactly o_zq's 33.55 MB
    f16* semHi = (f16*)o_zst;
    f16* semLo = semHi + (size_t)N_SEM * DIM;   //  = exactly o_zst's 33.55 MB

    k_prep<<<N_TOK + N_SEM + N_LEARN, 256, 0, stream>>>(
        x, invnx, xHi, xLo, sem, invnb, semHi, semLo, lrn, lrnHi, lrnLo, keys);

    dim3 g2(N_TOK / BM, (N_CODE + BN - 1) / BN);   // 32 x 33 (tail tile masked)
    k_gemm_mfma<<<g2, 512, 0, stream>>>(xHi, xLo, semHi, semLo, lrnHi, lrnLo,
                                        invnx, invnb, o_logits, keys);

    k_epilogue<<<N_TOK, 256, 0, stream>>>(x, sem, lrn, invnx, invnb, keys,
                                          o_idx, o_zq, o_zst, perTok);
    k_final<<<1, 256, 0, stream>>>(perTok, o_idx, o_scal);
}